// Round 1
// baseline (249.090 us; speedup 1.0000x reference)
//
#include <hip/hip_runtime.h>

// StrictProjectionBlock: per-3x3-matrix Frobenius normalize + 4 Newton-Schulz
// layers. Memory-bound: 288 MB total traffic -> ~46 us floor at 6.3 TB/s.
//
// Layout: x is (4e6, 9) fp32 row-major; matrix m occupies floats [9m, 9m+9).
// One thread per matrix. Coalescing fixed by LDS staging:
//   global float4 (coalesced) -> LDS -> 9 contiguous floats per thread.
// Stride-9 LDS access hits banks (9*lane+k)%32 — permutation (gcd(9,32)=1),
// so only the free 2-way wave64 aliasing (guide §2/G4).
// 4,000,000 % 256 == 0 -> exactly 15625 blocks, no tail handling.

#define NLAYERS 4

__global__ __launch_bounds__(256) void
proj_kernel(const float* __restrict__ x, float* __restrict__ out) {
    __shared__ float lds[256 * 9];              // 9216 B
    const int tid = threadIdx.x;
    const long long mbase = (long long)blockIdx.x * 256;  // first matrix of block

    // ---- stage 2304 floats = 576 float4, coalesced ----
    const float4* __restrict__ gin = (const float4*)(x + mbase * 9);
    float4* lds4 = (float4*)lds;
    lds4[tid]       = gin[tid];
    lds4[tid + 256] = gin[tid + 256];
    if (tid < 64) lds4[tid + 512] = gin[tid + 512];
    __syncthreads();

    // ---- per-thread matrix into registers ----
    float q[9];
#pragma unroll
    for (int k = 0; k < 9; ++k) q[k] = lds[tid * 9 + k];
    __syncthreads();   // everyone done reading before LDS is reused for output

    // ---- Frobenius normalize ----
    float s = 0.f;
#pragma unroll
    for (int k = 0; k < 9; ++k) s += q[k] * q[k];
    const float inv = rsqrtf(s);
#pragma unroll
    for (int k = 0; k < 9; ++k) q[k] *= inv;

    // ---- 4 Newton-Schulz layers ----
#pragma unroll
    for (int layer = 0; layer < NLAYERS; ++layer) {
        // N = Q^T Q (symmetric): N[i][k] = sum_j q[3j+i]*q[3j+k]
        float n00 = q[0]*q[0] + q[3]*q[3] + q[6]*q[6];
        float n01 = q[0]*q[1] + q[3]*q[4] + q[6]*q[7];
        float n02 = q[0]*q[2] + q[3]*q[5] + q[6]*q[8];
        float n11 = q[1]*q[1] + q[4]*q[4] + q[7]*q[7];
        float n12 = q[1]*q[2] + q[4]*q[5] + q[7]*q[8];
        float n22 = q[2]*q[2] + q[5]*q[5] + q[8]*q[8];
        float N[3][3] = {{n00, n01, n02}, {n01, n11, n12}, {n02, n12, n22}};

        // P = 0.5 * Q N
        float p[9];
#pragma unroll
        for (int i = 0; i < 3; ++i)
#pragma unroll
            for (int j = 0; j < 3; ++j)
                p[3*i+j] = 0.5f * (q[3*i+0]*N[0][j] + q[3*i+1]*N[1][j] + q[3*i+2]*N[2][j]);

        // R = P N;  Q = 2Q + R - 3P
        float r[9];
#pragma unroll
        for (int i = 0; i < 3; ++i)
#pragma unroll
            for (int j = 0; j < 3; ++j)
                r[3*i+j] = p[3*i+0]*N[0][j] + p[3*i+1]*N[1][j] + p[3*i+2]*N[2][j];

#pragma unroll
        for (int k = 0; k < 9; ++k) q[k] = 2.0f*q[k] + r[k] - 3.0f*p[k];
    }

    // ---- write back through LDS, coalesced float4 stores ----
#pragma unroll
    for (int k = 0; k < 9; ++k) lds[tid * 9 + k] = q[k];
    __syncthreads();

    float4* __restrict__ gout = (float4*)(out + mbase * 9);
    gout[tid]       = lds4[tid];
    gout[tid + 256] = lds4[tid + 256];
    if (tid < 64) gout[tid + 512] = lds4[tid + 512];
}

extern "C" void kernel_launch(void* const* d_in, const int* in_sizes, int n_in,
                              void* d_out, int out_size, void* d_ws, size_t ws_size,
                              hipStream_t stream) {
    const float* x = (const float*)d_in[0];
    float* out = (float*)d_out;
    const int nmat = in_sizes[0] / 9;        // 4,000,000
    const int blocks = nmat / 256;           // 15625 (exact)
    proj_kernel<<<blocks, 256, 0, stream>>>(x, out);
}

// Round 3
// 245.877 us; speedup vs baseline: 1.0131x; 1.0131x over previous
//
#include <hip/hip_runtime.h>

// StrictProjectionBlock: per-3x3-matrix Frobenius normalize + 4 Newton-Schulz
// layers. R1 counters: 90us, VALU-bound (VALUBusy 52% -> ~46us issue), HBM at
// 20-30% of peak, writes exactly 144MB, 0 bank conflicts.
//
// R2/R3 changes vs R1:
//  * Algebra: Q' = 2Q + PN - 3P, P = 0.5*Q*N  ==>  Q' = Q*M with
//    M = (0.5N - 1.5I)*N + 2I.  M is symmetric (polynomial in N), so only 6
//    entries; diag +2 folded into the fma accumulator. 69 ops/layer vs ~99.
//  * Separate in/out LDS buffers -> middle __syncthreads removed (3 -> 2).
//    18KB LDS/block still allows 8 blocks/CU (wave cap anyway).
//  * Nontemporal float4 stores for the output stream: don't let the 144MB of
//    written lines evict the (L3-resident) input between graph replays.
//    (R3 fix: __builtin_nontemporal_store needs a clang ext_vector type,
//    not HIP's float4 class -> use v4f.)
//
// Layout: one thread per matrix; coalesced float4 global <-> LDS staging;
// stride-9 LDS per-thread access is a bank permutation (gcd(9,32)=1) -> only
// the free 2-way wave64 aliasing (R1 measured SQ_LDS_BANK_CONFLICT = 0).
// 4,000,000 % 256 == 0 -> 15625 blocks, no tail.

#define NLAYERS 4

typedef float v4f __attribute__((ext_vector_type(4)));

__global__ __launch_bounds__(256) void
proj_kernel(const float* __restrict__ x, float* __restrict__ out) {
    __shared__ float lin[256 * 9];               // 9216 B
    __shared__ float lout[256 * 9];              // 9216 B
    const int tid = threadIdx.x;
    const long long mbase = (long long)blockIdx.x * 256;

    // ---- stage 2304 floats = 576 float4, coalesced ----
    const v4f* __restrict__ gin = (const v4f*)(x + mbase * 9);
    v4f* lin4 = (v4f*)lin;
    lin4[tid]       = gin[tid];
    lin4[tid + 256] = gin[tid + 256];
    if (tid < 64) lin4[tid + 512] = gin[tid + 512];
    __syncthreads();

    // ---- per-thread matrix into registers ----
    float q[9];
#pragma unroll
    for (int k = 0; k < 9; ++k) q[k] = lin[tid * 9 + k];

    // ---- Frobenius normalize ----
    float s = 0.f;
#pragma unroll
    for (int k = 0; k < 9; ++k) s = __builtin_fmaf(q[k], q[k], s);
    const float inv = rsqrtf(s);
#pragma unroll
    for (int k = 0; k < 9; ++k) q[k] *= inv;

    // ---- 4 Newton-Schulz layers: Q <- Q * ((0.5N - 1.5I)N + 2I) ----
#pragma unroll
    for (int layer = 0; layer < NLAYERS; ++layer) {
        // N = Q^T Q (symmetric, 6 entries)
        const float n00 = q[0]*q[0] + q[3]*q[3] + q[6]*q[6];
        const float n01 = q[0]*q[1] + q[3]*q[4] + q[6]*q[7];
        const float n02 = q[0]*q[2] + q[3]*q[5] + q[6]*q[8];
        const float n11 = q[1]*q[1] + q[4]*q[4] + q[7]*q[7];
        const float n12 = q[1]*q[2] + q[4]*q[5] + q[7]*q[8];
        const float n22 = q[2]*q[2] + q[5]*q[5] + q[8]*q[8];

        // A = 0.5*N - 1.5*I (symmetric)
        const float a00 = __builtin_fmaf(0.5f, n00, -1.5f);
        const float a11 = __builtin_fmaf(0.5f, n11, -1.5f);
        const float a22 = __builtin_fmaf(0.5f, n22, -1.5f);
        const float a01 = 0.5f * n01;
        const float a02 = 0.5f * n02;
        const float a12 = 0.5f * n12;

        // M = A*N + 2I (symmetric since A = p(N) commutes with N);
        // diag +2 folded into the fma accumulator start.
        const float m00 = __builtin_fmaf(a00,n00, __builtin_fmaf(a01,n01, __builtin_fmaf(a02,n02, 2.0f)));
        const float m01 = __builtin_fmaf(a00,n01, __builtin_fmaf(a01,n11, a02*n12));
        const float m02 = __builtin_fmaf(a00,n02, __builtin_fmaf(a01,n12, a02*n22));
        const float m11 = __builtin_fmaf(a01,n01, __builtin_fmaf(a11,n11, __builtin_fmaf(a12,n12, 2.0f)));
        const float m12 = __builtin_fmaf(a01,n02, __builtin_fmaf(a11,n12, a12*n22));
        const float m22 = __builtin_fmaf(a02,n02, __builtin_fmaf(a12,n12, __builtin_fmaf(a22,n22, 2.0f)));

        const float M[3][3] = {{m00, m01, m02}, {m01, m11, m12}, {m02, m12, m22}};

        // Q <- Q * M
        float qn[9];
#pragma unroll
        for (int i = 0; i < 3; ++i)
#pragma unroll
            for (int j = 0; j < 3; ++j)
                qn[3*i+j] = __builtin_fmaf(q[3*i+0], M[0][j],
                            __builtin_fmaf(q[3*i+1], M[1][j],
                                           q[3*i+2] * M[2][j]));
#pragma unroll
        for (int k = 0; k < 9; ++k) q[k] = qn[k];
    }

    // ---- write back through the second LDS buffer ----
#pragma unroll
    for (int k = 0; k < 9; ++k) lout[tid * 9 + k] = q[k];
    __syncthreads();

    // ---- coalesced nontemporal float4 stores ----
    v4f* __restrict__ gout = (v4f*)(out + mbase * 9);
    const v4f* lout4 = (const v4f*)lout;
    __builtin_nontemporal_store(lout4[tid],       gout + tid);
    __builtin_nontemporal_store(lout4[tid + 256], gout + tid + 256);
    if (tid < 64)
        __builtin_nontemporal_store(lout4[tid + 512], gout + tid + 512);
}

extern "C" void kernel_launch(void* const* d_in, const int* in_sizes, int n_in,
                              void* d_out, int out_size, void* d_ws, size_t ws_size,
                              hipStream_t stream) {
    const float* x = (const float*)d_in[0];
    float* out = (float*)d_out;
    const int nmat = in_sizes[0] / 9;        // 4,000,000
    const int blocks = nmat / 256;           // 15625 (exact)
    proj_kernel<<<blocks, 256, 0, stream>>>(x, out);
}